// Round 18
// baseline (148.536 us; speedup 1.0000x reference)
//
#include <hip/hip_runtime.h>
#include <hip/hip_bf16.h>

typedef __attribute__((ext_vector_type(8))) short bf16x8;
typedef __attribute__((ext_vector_type(4))) float f32x4;

#define DIN 24
#define DOUT 47
#define SPD 2209
#define CIN 32
#define COUT 64
#define SP_IN 13824
#define SP_OUT 103823
#define GROUPS 8
#define WPK_OFF 512
#define LROW 40          // elems per (plane,iw) row: 32 ci + 8 pad (80B, 16B-aligned)
#define PLANE 1000       // 25 rows * LROW (iw 0..23 data, iw=24 zero row)

__device__ __forceinline__ unsigned short f2bf(float v) {
    __hip_bfloat16 h = __float2bfloat16(v);
    return *(const unsigned short*)&h;
}

__device__ __forceinline__ float hswish(float z) {
    float c = fminf(fmaxf(z + 3.f, 0.f), 6.f);
    return z * c * (1.f / 6.f);
}

__device__ __forceinline__ float swish(float v) {
    // v * sigmoid(v) with HW v_rcp_f32 (~1ulp) instead of software fp div
    return v * __builtin_amdgcn_rcpf(1.f + __expf(-v));
}

// wpk[tap][coblk][lane][j]: A-frag bf16, co = coblk*16+(lane&15), ci = (lane>>4)*8+j
// Also zeroes the 128-float stats region (block 0).
__global__ __launch_bounds__(256)
void repack_w(const float* __restrict__ w, unsigned short* __restrict__ wpk,
              float* __restrict__ stats)
{
    if (blockIdx.x == 0 && threadIdx.x < 128) stats[threadIdx.x] = 0.f;
    int i = blockIdx.x * 256 + threadIdx.x;
    if (i >= 27 * 4 * 64 * 8) return;
    int j = i & 7;
    int lane = (i >> 3) & 63;
    int coblk = (i >> 9) & 3;
    int tap = i >> 11;
    int kw = tap % 3, kh = (tap / 3) % 3, kd = tap / 9;
    int co = coblk * 16 + (lane & 15);
    int ci = (lane >> 4) * 8 + j;
    wpk[i] = f2bf(w[(((co * CIN + ci) * 3 + kd) * 3 + kh) * 3 + kw]);
}

#define MFMA16(A, B, C) __builtin_amdgcn_mfma_f32_16x16x32_bf16(A, B, C, 0, 0, 0)

__global__ __launch_bounds__(256, 3)
void conv_f32(const float* __restrict__ x, const unsigned short* __restrict__ wpk,
              const float* __restrict__ bias, float* __restrict__ y,
              float* __restrict__ stats)
{
    __shared__ unsigned short xs[15 * PLANE];   // 30000 B

    const int bx = blockIdx.x;                  // 12 od-slabs * 6 oh-slabs
    const int t = bx / 6;                       // od slab [4t, 4t+4)
    const int s = bx - t * 6;                   // oh slab [8s, 8s+8)
    const int n = blockIdx.z;
    const int tid = threadIdx.x;

    // ---- stage 15 planes (idl 0..2, ihl 0..4) x 24 iw x 32 ci, fp32->bf16 transpose
    const float* xb = x + (size_t)n * (CIN * SP_IN);
    for (int i = tid; i < 2880; i += 256) {
        int ci = i & 31;
        int rest = i >> 5;                      // 0..89
        int j = rest % 6;
        int pl = rest / 6;                      // 0..14
        int ihl = pl % 5, idl = pl / 5;
        int id = min(2 * t + idl, 23);
        int ih = min(4 * s + ihl, 23);
        const float4 v = *(const float4*)(xb + ci * SP_IN + (id * DIN + ih) * DIN + 4 * j);
        int base = pl * PLANE + (4 * j) * LROW + ci;
        xs[base + 0 * LROW] = f2bf(v.x);
        xs[base + 1 * LROW] = f2bf(v.y);
        xs[base + 2 * LROW] = f2bf(v.z);
        xs[base + 3 * LROW] = f2bf(v.w);
    }
    for (int i = tid; i < 480; i += 256) {      // zero row iw=24 per plane
        xs[(i >> 5) * PLANE + 24 * LROW + (i & 31)] = 0;
    }
    __syncthreads();

    const int lane = tid & 63;
    const int cb = tid >> 6;                    // wave = co block (16 co)
    const int col = lane & 15;
    const int kg = lane >> 4;

    // per-kw A-frag base (per-lane): wpk + kw*2048 + cb*512 + lane*8,
    // then af(kd,kh) at +(kd*3+kh)*6144 elements
    const unsigned short* wb = wpk + (size_t)cb * 512 + (size_t)lane * 8;

    const f32x4 bv = *(const f32x4*)&bias[cb * 16 + kg * 4];
    const size_t cob = ((size_t)n * COUT + cb * 16 + kg * 4) * SP_OUT;
    float s1 = 0.f, s2 = 0.f;

    auto strow = [&](const f32x4 (&A)[3], int od, int oh) {
        const size_t rb = cob + (size_t)od * SPD + (size_t)oh * DOUT;
        #pragma unroll
        for (int w = 0; w < 3; ++w) {
            const int ow = 16 * w + col;
            const bool v = (ow < DOUT);
            #pragma unroll
            for (int j = 0; j < 4; ++j) {
                float val = A[w][j] + bv[j];
                float sw = swish(val);
                if (v) {
                    y[rb + (size_t)j * SP_OUT + ow] = sw;
                    s1 += sw;
                    s2 += sw * sw;
                }
            }
        }
    };

    #pragma unroll
    for (int e = 0; e < 2; ++e) {
        const int od0 = 4 * t + 2 * e;          // even od, always valid
        const bool odOv = (od0 + 1 < DOUT);
        #pragma unroll
        for (int bh = 0; bh < 4; ++bh) {
            const int ohE = 8 * s + 2 * bh;     // even oh, always valid
            const int ohO = ohE + 1;
            const bool ohOv = (ohO < DOUT);
            // planes: P00 (kd in {1,2}, kh in {1,2}); P01 (kh=0); P10 (kd=0); P11 (both)
            const int p00 = (e * 5 + bh) * PLANE;
            const int p01 = p00 + PLANE;
            const int p10 = p00 + 5 * PLANE;
            const int p11 = p10 + PLANE;

            f32x4 aEE[3], aEO[3], aOE[3], aOO[3];
            #pragma unroll
            for (int w = 0; w < 3; ++w) {
                aEE[w] = (f32x4){0.f, 0.f, 0.f, 0.f};
                aEO[w] = (f32x4){0.f, 0.f, 0.f, 0.f};
                aOE[w] = (f32x4){0.f, 0.f, 0.f, 0.f};
                aOO[w] = (f32x4){0.f, 0.f, 0.f, 0.f};
            }

            #pragma unroll 1
            for (int kw = 0; kw < 3; ++kw) {
                // stream this kw's 9 A-frags from L2/L3 (36 VGPR transient)
                const unsigned short* wq = wb + kw * 2048;
                asm volatile("" : "+v"(wq));
                const bf16x8 A00 = *(const bf16x8*)&wq[0 * 6144];
                const bf16x8 A01 = *(const bf16x8*)&wq[1 * 6144];
                const bf16x8 A02 = *(const bf16x8*)&wq[2 * 6144];
                const bf16x8 A10 = *(const bf16x8*)&wq[3 * 6144];
                const bf16x8 A11 = *(const bf16x8*)&wq[4 * 6144];
                const bf16x8 A12 = *(const bf16x8*)&wq[5 * 6144];
                const bf16x8 A20 = *(const bf16x8*)&wq[6 * 6144];
                const bf16x8 A21 = *(const bf16x8*)&wq[7 * 6144];
                const bf16x8 A22 = *(const bf16x8*)&wq[8 * 6144];

                #pragma unroll
                for (int w = 0; w < 3; ++w) {
                    const int num = col + 1 - kw;
                    const bool pv = ((num & 1) == 0);
                    const int iw = 8 * w + (num >> 1);
                    const int o = ((pv && iw <= 24) ? iw : 24) * LROW + kg * 8;

                    const bf16x8 b0 = *(const bf16x8*)&xs[p00 + o];
                    aEE[w] = MFMA16(A11, b0, aEE[w]);
                    aEO[w] = MFMA16(A12, b0, aEO[w]);
                    aOE[w] = MFMA16(A21, b0, aOE[w]);
                    aOO[w] = MFMA16(A22, b0, aOO[w]);
                    const bf16x8 b1 = *(const bf16x8*)&xs[p01 + o];
                    aEO[w] = MFMA16(A10, b1, aEO[w]);
                    aOO[w] = MFMA16(A20, b1, aOO[w]);
                    const bf16x8 b2 = *(const bf16x8*)&xs[p10 + o];
                    aOE[w] = MFMA16(A01, b2, aOE[w]);
                    aOO[w] = MFMA16(A02, b2, aOO[w]);
                    const bf16x8 b3 = *(const bf16x8*)&xs[p11 + o];
                    aOO[w] = MFMA16(A00, b3, aOO[w]);
                }
            }

            strow(aEE, od0, ohE);
            if (ohOv) strow(aEO, od0, ohO);
            if (odOv) strow(aOE, od0 + 1, ohE);
            if (odOv && ohOv) strow(aOO, od0 + 1, ohO);
        }
    }

    // stats: lanes 0-31 (kg 0,1) -> group 2cb; lanes 32-63 -> 2cb+1
    #pragma unroll
    for (int o = 16; o; o >>= 1) {
        s1 += __shfl_down(s1, o);
        s2 += __shfl_down(s2, o);
    }
    if ((lane & 31) == 0) {
        const int g = cb * 2 + (lane >> 5);
        atomicAdd(&stats[(n * GROUPS + g) * 2 + 0], s1);
        atomicAdd(&stats[(n * GROUPS + g) * 2 + 1], s2);
    }
}

__global__ __launch_bounds__(256)
void norm_ip(float* __restrict__ y, const float* __restrict__ stats)
{
    const int total4 = (8 * COUT * SP_OUT) / 4;
    const int grp4 = (8 * SP_OUT) / 4;
    const float inv_cnt = 1.0f / (8.0f * (float)SP_OUT);
    float4* p = (float4*)y;
    int idx = blockIdx.x * 256 + threadIdx.x;
    const int stride = gridDim.x * 256;
    for (int i = idx; i < total4; i += stride) {
        const int ng = i / grp4;
        const float m1 = stats[ng * 2 + 0] * inv_cnt;
        const float m2 = stats[ng * 2 + 1] * inv_cnt;
        const float rstd = rsqrtf(m2 - m1 * m1 + 1e-5f);
        float4 v = p[i];
        v.x = hswish((v.x - m1) * rstd);
        v.y = hswish((v.y - m1) * rstd);
        v.z = hswish((v.z - m1) * rstd);
        v.w = hswish((v.w - m1) * rstd);
        p[i] = v;
    }
}

extern "C" void kernel_launch(void* const* d_in, const int* in_sizes, int n_in,
                              void* d_out, int out_size, void* d_ws, size_t ws_size,
                              hipStream_t stream)
{
    const float* x    = (const float*)d_in[0];
    const float* w    = (const float*)d_in[1];
    const float* bias = (const float*)d_in[2];
    float* stats = (float*)d_ws;
    unsigned short* wpk = (unsigned short*)((char*)d_ws + WPK_OFF);
    float* y = (float*)d_out;

    repack_w<<<216, 256, 0, stream>>>(w, wpk, stats);
    conv_f32<<<dim3(12 * 6, 1, 8), 256, 0, stream>>>(x, wpk, bias, y, stats);
    norm_ip<<<2048, 256, 0, stream>>>(y, stats);
}

// Round 19
// 131.307 us; speedup vs baseline: 1.1312x; 1.1312x over previous
//
#include <hip/hip_runtime.h>
#include <hip/hip_bf16.h>

typedef __attribute__((ext_vector_type(8))) short bf16x8;
typedef __attribute__((ext_vector_type(4))) float f32x4;

#define DIN 24
#define DOUT 47
#define SPD 2209
#define CIN 32
#define COUT 64
#define SP_IN 13824
#define SP_OUT 103823
#define GROUPS 8
#define WPK_OFF 512
#define Y_OFF 131072
#define LROW 40          // elems per (plane,iw) row: 32 ci + 8 pad (80B, 16B-aligned)
#define PLANE 1000       // 25 rows * LROW (iw 0..23 data, iw=24 zero row)

__device__ __forceinline__ unsigned short f2bf(float v) {
    __hip_bfloat16 h = __float2bfloat16(v);
    return *(const unsigned short*)&h;
}

__device__ __forceinline__ float hswish(float z) {
    float c = fminf(fmaxf(z + 3.f, 0.f), 6.f);
    return z * c * (1.f / 6.f);
}

__device__ __forceinline__ float swish(float v) {
    // v * sigmoid(v) with HW v_rcp_f32 (~1ulp) instead of software fp div
    return v * __builtin_amdgcn_rcpf(1.f + __expf(-v));
}

// wpk[tap][coblk][lane][j]: A-frag bf16, co = coblk*16+(lane&15), ci = (lane>>4)*8+j
// Block 0 also zeroes the 128-float stats region.
__global__ __launch_bounds__(256)
void repack_w(const float* __restrict__ w, unsigned short* __restrict__ wpk,
              float* __restrict__ stats)
{
    if (blockIdx.x == 0 && threadIdx.x < 128) stats[threadIdx.x] = 0.f;
    int i = blockIdx.x * 256 + threadIdx.x;
    if (i >= 27 * 4 * 64 * 8) return;
    int j = i & 7;
    int lane = (i >> 3) & 63;
    int coblk = (i >> 9) & 3;
    int tap = i >> 11;
    int kw = tap % 3, kh = (tap / 3) % 3, kd = tap / 9;
    int co = coblk * 16 + (lane & 15);
    int ci = (lane >> 4) * 8 + j;
    wpk[i] = f2bf(w[(((co * CIN + ci) * 3 + kd) * 3 + kh) * 3 + kw]);
}

#define MFMA16(A, B, C) __builtin_amdgcn_mfma_f32_16x16x32_bf16(A, B, C, 0, 0, 0)

template<bool B16>
__global__ __launch_bounds__(256, 3)
void conv_mfma(const float* __restrict__ x, const unsigned short* __restrict__ wpk,
               const float* __restrict__ bias, char* __restrict__ yb,
               float* __restrict__ stats)
{
    __shared__ unsigned short xs[15 * PLANE];   // 30000 B

    const int bx = blockIdx.x;                  // 12 od-slabs * 6 oh-slabs
    const int t = bx / 6;                       // od slab [4t, 4t+4)
    const int s = bx - t * 6;                   // oh slab [8s, 8s+8)
    const int n = blockIdx.z;
    const int tid = threadIdx.x;

    // ---- stage 15 planes (idl 0..2, ihl 0..4) x 24 iw x 32 ci, fp32->bf16 transpose
    // j-fastest lane map: 6 consecutive lanes cover a 96B contiguous run (coalesced);
    // LDS writes are exactly 2-way banked (free, m136).
    const float* xb = x + (size_t)n * (CIN * SP_IN);
    for (int i = tid; i < 2880; i += 256) {
        int j = i % 6;
        int r = i / 6;
        int ci = r & 31;
        int pl = r >> 5;                        // 0..14
        int ihl = pl % 5, idl = pl / 5;
        int id = min(2 * t + idl, 23);
        int ih = min(4 * s + ihl, 23);
        const float4 v = *(const float4*)(xb + ci * SP_IN + (id * DIN + ih) * DIN + 4 * j);
        int base = pl * PLANE + (4 * j) * LROW + ci;
        xs[base + 0 * LROW] = f2bf(v.x);
        xs[base + 1 * LROW] = f2bf(v.y);
        xs[base + 2 * LROW] = f2bf(v.z);
        xs[base + 3 * LROW] = f2bf(v.w);
    }
    for (int i = tid; i < 480; i += 256) {      // zero row iw=24 per plane
        xs[(i >> 5) * PLANE + 24 * LROW + (i & 31)] = 0;
    }
    __syncthreads();

    const int lane = tid & 63;
    const int cb = tid >> 6;                    // wave = co block (16 co)
    const int col = lane & 15;
    const int kg = lane >> 4;

    // per-kw A-frag base (per-lane): wpk + kw*2048 + cb*512 + lane*8,
    // then af(kd,kh) at +(kd*3+kh)*6144 elements
    const unsigned short* wb = wpk + (size_t)cb * 512 + (size_t)lane * 8;

    // precomputed B row offsets (zero row 24 when (col,kw) parity-invalid)
    int off[3][3];
    #pragma unroll
    for (int w = 0; w < 3; ++w)
        #pragma unroll
        for (int kw = 0; kw < 3; ++kw) {
            int num = col + 1 - kw;
            bool pv = ((num & 1) == 0);
            int iw = 8 * w + (num >> 1);
            off[w][kw] = ((pv && iw <= 24) ? iw : 24) * LROW + kg * 8;
        }

    const f32x4 bv = *(const f32x4*)&bias[cb * 16 + kg * 4];
    const size_t cob = ((size_t)n * COUT + cb * 16 + kg * 4) * SP_OUT;
    float s1 = 0.f, s2 = 0.f;

    auto strow = [&](const f32x4 (&A)[3], int od, int oh) {
        const size_t rb = cob + (size_t)od * SPD + (size_t)oh * DOUT;
        #pragma unroll
        for (int w = 0; w < 3; ++w) {
            const int ow = 16 * w + col;
            const bool v = (ow < DOUT);
            #pragma unroll
            for (int j = 0; j < 4; ++j) {
                float val = A[w][j] + bv[j];
                float sw = swish(val);
                if (v) {
                    if (B16)
                        ((unsigned short*)yb)[rb + (size_t)j * SP_OUT + ow] = f2bf(sw);
                    else
                        ((float*)yb)[rb + (size_t)j * SP_OUT + ow] = sw;
                    s1 += sw;
                    s2 += sw * sw;
                }
            }
        }
    };

    #pragma unroll
    for (int e = 0; e < 2; ++e) {
        const int od0 = 4 * t + 2 * e;          // even od, always valid
        const bool odOv = (od0 + 1 < DOUT);
        #pragma unroll
        for (int bh = 0; bh < 4; ++bh) {
            const int ohE = 8 * s + 2 * bh;     // even oh, always valid
            const int ohO = ohE + 1;
            const bool ohOv = (ohO < DOUT);
            // planes: P00 (kd in {1,2}, kh in {1,2}); P01 (kh=0); P10 (kd=0); P11 (both)
            const int p00 = (e * 5 + bh) * PLANE;
            const int p01 = p00 + PLANE;
            const int p10 = p00 + 5 * PLANE;
            const int p11 = p10 + PLANE;

            f32x4 aEE[3], aEO[3], aOE[3], aOO[3];
            #pragma unroll
            for (int w = 0; w < 3; ++w) {
                aEE[w] = (f32x4){0.f, 0.f, 0.f, 0.f};
                aEO[w] = (f32x4){0.f, 0.f, 0.f, 0.f};
                aOE[w] = (f32x4){0.f, 0.f, 0.f, 0.f};
                aOO[w] = (f32x4){0.f, 0.f, 0.f, 0.f};
            }

            #pragma unroll 1
            for (int kw = 0; kw < 3; ++kw) {
                // stream this kw's 9 A-frags from L2/L3 (36 VGPR transient)
                const unsigned short* wq = wb + kw * 2048;
                asm volatile("" : "+v"(wq));
                const bf16x8 A00 = *(const bf16x8*)&wq[0 * 6144];
                const bf16x8 A01 = *(const bf16x8*)&wq[1 * 6144];
                const bf16x8 A02 = *(const bf16x8*)&wq[2 * 6144];
                const bf16x8 A10 = *(const bf16x8*)&wq[3 * 6144];
                const bf16x8 A11 = *(const bf16x8*)&wq[4 * 6144];
                const bf16x8 A12 = *(const bf16x8*)&wq[5 * 6144];
                const bf16x8 A20 = *(const bf16x8*)&wq[6 * 6144];
                const bf16x8 A21 = *(const bf16x8*)&wq[7 * 6144];
                const bf16x8 A22 = *(const bf16x8*)&wq[8 * 6144];

                #pragma unroll
                for (int w = 0; w < 3; ++w) {
                    const int o = off[w][kw];

                    const bf16x8 b0 = *(const bf16x8*)&xs[p00 + o];
                    aEE[w] = MFMA16(A11, b0, aEE[w]);
                    aEO[w] = MFMA16(A12, b0, aEO[w]);
                    aOE[w] = MFMA16(A21, b0, aOE[w]);
                    aOO[w] = MFMA16(A22, b0, aOO[w]);
                    const bf16x8 b1 = *(const bf16x8*)&xs[p01 + o];
                    aEO[w] = MFMA16(A10, b1, aEO[w]);
                    aOO[w] = MFMA16(A20, b1, aOO[w]);
                    const bf16x8 b2 = *(const bf16x8*)&xs[p10 + o];
                    aOE[w] = MFMA16(A01, b2, aOE[w]);
                    aOO[w] = MFMA16(A02, b2, aOO[w]);
                    const bf16x8 b3 = *(const bf16x8*)&xs[p11 + o];
                    aOO[w] = MFMA16(A00, b3, aOO[w]);
                }
            }

            strow(aEE, od0, ohE);
            if (ohOv) strow(aEO, od0, ohO);
            if (odOv) strow(aOE, od0 + 1, ohE);
            if (odOv && ohOv) strow(aOO, od0 + 1, ohO);
        }
    }

    // stats: lanes 0-31 (kg 0,1) -> group 2cb; lanes 32-63 -> 2cb+1
    #pragma unroll
    for (int o = 16; o; o >>= 1) {
        s1 += __shfl_down(s1, o);
        s2 += __shfl_down(s2, o);
    }
    if ((lane & 31) == 0) {
        const int g = cb * 2 + (lane >> 5);
        atomicAdd(&stats[(n * GROUPS + g) * 2 + 0], s1);
        atomicAdd(&stats[(n * GROUPS + g) * 2 + 1], s2);
    }
}

__global__ __launch_bounds__(256)
void norm_bf16(const unsigned short* __restrict__ yb,
               const float* __restrict__ stats, float* __restrict__ out)
{
    const int total8 = 8 * COUT * SP_OUT / 8;
    const int grp8 = SP_OUT;
    const float inv_cnt = 1.0f / (8.0f * (float)SP_OUT);
    int idx = blockIdx.x * 256 + threadIdx.x;
    const int stride = gridDim.x * 256;
    for (int i = idx; i < total8; i += stride) {
        const int ng = i / grp8;
        const float m1 = stats[ng * 2 + 0] * inv_cnt;
        const float m2 = stats[ng * 2 + 1] * inv_cnt;
        const float rstd = rsqrtf(m2 - m1 * m1 + 1e-5f);
        const uint4 v = ((const uint4*)yb)[i];
        float4 o0, o1;
        o0.x = hswish((__uint_as_float((v.x & 0xffffu) << 16) - m1) * rstd);
        o0.y = hswish((__uint_as_float((v.x >> 16) << 16) - m1) * rstd);
        o0.z = hswish((__uint_as_float((v.y & 0xffffu) << 16) - m1) * rstd);
        o0.w = hswish((__uint_as_float((v.y >> 16) << 16) - m1) * rstd);
        o1.x = hswish((__uint_as_float((v.z & 0xffffu) << 16) - m1) * rstd);
        o1.y = hswish((__uint_as_float((v.z >> 16) << 16) - m1) * rstd);
        o1.z = hswish((__uint_as_float((v.w & 0xffffu) << 16) - m1) * rstd);
        o1.w = hswish((__uint_as_float((v.w >> 16) << 16) - m1) * rstd);
        ((float4*)out)[2 * i + 0] = o0;
        ((float4*)out)[2 * i + 1] = o1;
    }
}

__global__ __launch_bounds__(256)
void norm_ip(float* __restrict__ y, const float* __restrict__ stats)
{
    const int total4 = (8 * COUT * SP_OUT) / 4;
    const int grp4 = (8 * SP_OUT) / 4;
    const float inv_cnt = 1.0f / (8.0f * (float)SP_OUT);
    float4* p = (float4*)y;
    int idx = blockIdx.x * 256 + threadIdx.x;
    const int stride = gridDim.x * 256;
    for (int i = idx; i < total4; i += stride) {
        const int ng = i / grp4;
        const float m1 = stats[ng * 2 + 0] * inv_cnt;
        const float m2 = stats[ng * 2 + 1] * inv_cnt;
        const float rstd = rsqrtf(m2 - m1 * m1 + 1e-5f);
        float4 v = p[i];
        v.x = hswish((v.x - m1) * rstd);
        v.y = hswish((v.y - m1) * rstd);
        v.z = hswish((v.z - m1) * rstd);
        v.w = hswish((v.w - m1) * rstd);
        p[i] = v;
    }
}

extern "C" void kernel_launch(void* const* d_in, const int* in_sizes, int n_in,
                              void* d_out, int out_size, void* d_ws, size_t ws_size,
                              hipStream_t stream)
{
    const float* x    = (const float*)d_in[0];
    const float* w    = (const float*)d_in[1];
    const float* bias = (const float*)d_in[2];
    float* stats = (float*)d_ws;
    unsigned short* wpk = (unsigned short*)((char*)d_ws + WPK_OFF);

    repack_w<<<216, 256, 0, stream>>>(w, wpk, stats);

    dim3 grid(12 * 6, 1, 8);
    const size_t need = (size_t)Y_OFF + (size_t)8 * COUT * SP_OUT * 2;
    if (ws_size >= need) {
        char* ybf = (char*)d_ws + Y_OFF;
        conv_mfma<true><<<grid, 256, 0, stream>>>(x, wpk, bias, ybf, stats);
        norm_bf16<<<2048, 256, 0, stream>>>((const unsigned short*)ybf, stats, (float*)d_out);
    } else {
        conv_mfma<false><<<grid, 256, 0, stream>>>(x, wpk, bias, (char*)d_out, stats);
        norm_ip<<<2048, 256, 0, stream>>>((float*)d_out, stats);
    }
}

// Round 20
// 131.099 us; speedup vs baseline: 1.1330x; 1.0016x over previous
//
#include <hip/hip_runtime.h>
#include <hip/hip_bf16.h>

typedef __attribute__((ext_vector_type(8))) short bf16x8;
typedef __attribute__((ext_vector_type(4))) float f32x4;

#define DIN 24
#define DOUT 47
#define SPD 2209
#define CIN 32
#define COUT 64
#define SP_IN 13824
#define SP_OUT 103823
#define GROUPS 8
#define WPK_OFF 512
#define Y_OFF 131072
#define LROW 40          // elems per (plane,iw) row: 32 ci + 8 pad (80B, 16B-aligned)
#define PLANE 1000       // 25 rows * LROW (iw 0..23 data, iw=24 zero row)

__device__ __forceinline__ unsigned short f2bf(float v) {
    __hip_bfloat16 h = __float2bfloat16(v);
    return *(const unsigned short*)&h;
}

__device__ __forceinline__ float hswish(float z) {
    float c = fminf(fmaxf(z + 3.f, 0.f), 6.f);
    return z * c * (1.f / 6.f);
}

__device__ __forceinline__ float swish(float v) {
    return v * __builtin_amdgcn_rcpf(1.f + __expf(-v));
}

// wpk[tap][coblk][lane][j]: A-frag bf16, co = coblk*16+(lane&15), ci = (lane>>4)*8+j
// Block 0 also zeroes the 128-float stats region.
__global__ __launch_bounds__(256)
void repack_w(const float* __restrict__ w, unsigned short* __restrict__ wpk,
              float* __restrict__ stats)
{
    if (blockIdx.x == 0 && threadIdx.x < 128) stats[threadIdx.x] = 0.f;
    int i = blockIdx.x * 256 + threadIdx.x;
    if (i >= 27 * 4 * 64 * 8) return;
    int j = i & 7;
    int lane = (i >> 3) & 63;
    int coblk = (i >> 9) & 3;
    int tap = i >> 11;
    int kw = tap % 3, kh = (tap / 3) % 3, kd = tap / 9;
    int co = coblk * 16 + (lane & 15);
    int ci = (lane >> 4) * 8 + j;
    wpk[i] = f2bf(w[(((co * CIN + ci) * 3 + kd) * 3 + kh) * 3 + kw]);
}

#define MFMA16(A, B, C) __builtin_amdgcn_mfma_f32_16x16x32_bf16(A, B, C, 0, 0, 0)

// load 9 A-frags (tap = kd*3+kh in [0,9)) for a given kw into buffer B##0..B##8
#define LOADA(B, KW) do { \
    const unsigned short* wq = wb + (KW) * 2048; \
    asm volatile("" : "+v"(wq)); \
    B##0 = *(const bf16x8*)&wq[0 * 6144]; \
    B##1 = *(const bf16x8*)&wq[1 * 6144]; \
    B##2 = *(const bf16x8*)&wq[2 * 6144]; \
    B##3 = *(const bf16x8*)&wq[3 * 6144]; \
    B##4 = *(const bf16x8*)&wq[4 * 6144]; \
    B##5 = *(const bf16x8*)&wq[5 * 6144]; \
    B##6 = *(const bf16x8*)&wq[6 * 6144]; \
    B##7 = *(const bf16x8*)&wq[7 * 6144]; \
    B##8 = *(const bf16x8*)&wq[8 * 6144]; \
} while (0)

// 27 MFMAs for one kw using buffer B (B##t, t = kd*3+kh)
#define MBLK(B, KW) do { \
    _Pragma("unroll") \
    for (int w = 0; w < 3; ++w) { \
        const int o = off[w][KW]; \
        const bf16x8 b0 = *(const bf16x8*)&xs[p00 + o]; \
        aEE[w] = MFMA16(B##4, b0, aEE[w]); \
        aEO[w] = MFMA16(B##5, b0, aEO[w]); \
        aOE[w] = MFMA16(B##7, b0, aOE[w]); \
        aOO[w] = MFMA16(B##8, b0, aOO[w]); \
        const bf16x8 b1 = *(const bf16x8*)&xs[p01 + o]; \
        aEO[w] = MFMA16(B##3, b1, aEO[w]); \
        aOO[w] = MFMA16(B##6, b1, aOO[w]); \
        const bf16x8 b2 = *(const bf16x8*)&xs[p10 + o]; \
        aOE[w] = MFMA16(B##1, b2, aOE[w]); \
        aOO[w] = MFMA16(B##2, b2, aOO[w]); \
        const bf16x8 b3 = *(const bf16x8*)&xs[p11 + o]; \
        aOO[w] = MFMA16(B##0, b3, aOO[w]); \
    } \
} while (0)

template<bool B16>
__global__ __launch_bounds__(256, 3)
void conv_mfma(const float* __restrict__ x, const unsigned short* __restrict__ wpk,
               const float* __restrict__ bias, char* __restrict__ yb,
               float* __restrict__ stats)
{
    __shared__ unsigned short xs[15 * PLANE];   // 30000 B

    const int bx = blockIdx.x;                  // 12 od-slabs * 6 oh-slabs
    const int t = bx / 6;                       // od slab [4t, 4t+4)
    const int s = bx - t * 6;                   // oh slab [8s, 8s+8)
    const int n = blockIdx.z;
    const int tid = threadIdx.x;

    // ---- stage 15 planes (idl 0..2, ihl 0..4) x 24 iw x 32 ci, fp32->bf16 transpose
    // j-fastest lane map: 6 consecutive lanes cover a 96B contiguous run (coalesced)
    const float* xb = x + (size_t)n * (CIN * SP_IN);
    for (int i = tid; i < 2880; i += 256) {
        int j = i % 6;
        int r = i / 6;
        int ci = r & 31;
        int pl = r >> 5;                        // 0..14
        int ihl = pl % 5, idl = pl / 5;
        int id = min(2 * t + idl, 23);
        int ih = min(4 * s + ihl, 23);
        const float4 v = *(const float4*)(xb + ci * SP_IN + (id * DIN + ih) * DIN + 4 * j);
        int base = pl * PLANE + (4 * j) * LROW + ci;
        xs[base + 0 * LROW] = f2bf(v.x);
        xs[base + 1 * LROW] = f2bf(v.y);
        xs[base + 2 * LROW] = f2bf(v.z);
        xs[base + 3 * LROW] = f2bf(v.w);
    }
    for (int i = tid; i < 480; i += 256) {      // zero row iw=24 per plane
        xs[(i >> 5) * PLANE + 24 * LROW + (i & 31)] = 0;
    }
    __syncthreads();

    const int lane = tid & 63;
    const int cb = tid >> 6;                    // wave = co block (16 co)
    const int col = lane & 15;
    const int kg = lane >> 4;

    const unsigned short* wb = wpk + (size_t)cb * 512 + (size_t)lane * 8;

    // precomputed B row offsets (zero row 24 when (col,kw) parity-invalid)
    int off[3][3];
    #pragma unroll
    for (int w = 0; w < 3; ++w)
        #pragma unroll
        for (int kw = 0; kw < 3; ++kw) {
            int num = col + 1 - kw;
            bool pv = ((num & 1) == 0);
            int iw = 8 * w + (num >> 1);
            off[w][kw] = ((pv && iw <= 24) ? iw : 24) * LROW + kg * 8;
        }

    const f32x4 bv = *(const f32x4*)&bias[cb * 16 + kg * 4];
    const size_t cob = ((size_t)n * COUT + cb * 16 + kg * 4) * SP_OUT;
    float s1 = 0.f, s2 = 0.f;

    auto strow = [&](const f32x4 (&A)[3], int od, int oh) {
        const size_t rb = cob + (size_t)od * SPD + (size_t)oh * DOUT;
        #pragma unroll
        for (int w = 0; w < 3; ++w) {
            const int ow = 16 * w + col;
            const bool v = (ow < DOUT);
            #pragma unroll
            for (int j = 0; j < 4; ++j) {
                float val = A[w][j] + bv[j];
                float sw = swish(val);
                if (v) {
                    if (B16)
                        ((unsigned short*)yb)[rb + (size_t)j * SP_OUT + ow] = f2bf(sw);
                    else
                        ((float*)yb)[rb + (size_t)j * SP_OUT + ow] = sw;
                    s1 += sw;
                    s2 += sw * sw;
                }
            }
        }
    };

    #pragma unroll
    for (int e = 0; e < 2; ++e) {
        const int od0 = 4 * t + 2 * e;          // even od, always valid
        const bool odOv = (od0 + 1 < DOUT);
        #pragma unroll
        for (int bh = 0; bh < 4; ++bh) {
            const int ohE = 8 * s + 2 * bh;     // even oh, always valid
            const int ohO = ohE + 1;
            const bool ohOv = (ohO < DOUT);
            // planes: P00 (kd in {1,2}, kh in {1,2}); P01 (kh=0); P10 (kd=0); P11 (both)
            const int p00 = (e * 5 + bh) * PLANE;
            const int p01 = p00 + PLANE;
            const int p10 = p00 + 5 * PLANE;
            const int p11 = p10 + PLANE;

            f32x4 aEE[3], aEO[3], aOE[3], aOO[3];
            #pragma unroll
            for (int w = 0; w < 3; ++w) {
                aEE[w] = (f32x4){0.f, 0.f, 0.f, 0.f};
                aEO[w] = (f32x4){0.f, 0.f, 0.f, 0.f};
                aOE[w] = (f32x4){0.f, 0.f, 0.f, 0.f};
                aOO[w] = (f32x4){0.f, 0.f, 0.f, 0.f};
            }

            // 2-deep software pipeline over kw: loads of kw+1 in flight
            // under kw's MFMAs (never drain before each burst)
            {
                bf16x8 AX0, AX1, AX2, AX3, AX4, AX5, AX6, AX7, AX8;
                bf16x8 AY0, AY1, AY2, AY3, AY4, AY5, AY6, AY7, AY8;
                LOADA(AX, 0);
                LOADA(AY, 1);
                MBLK(AX, 0);
                LOADA(AX, 2);
                MBLK(AY, 1);
                MBLK(AX, 2);
            }

            strow(aEE, od0, ohE);
            if (ohOv) strow(aEO, od0, ohO);
            if (odOv) strow(aOE, od0 + 1, ohE);
            if (odOv && ohOv) strow(aOO, od0 + 1, ohO);
        }
    }

    // stats: lanes 0-31 (kg 0,1) -> group 2cb; lanes 32-63 -> 2cb+1
    #pragma unroll
    for (int o = 16; o; o >>= 1) {
        s1 += __shfl_down(s1, o);
        s2 += __shfl_down(s2, o);
    }
    if ((lane & 31) == 0) {
        const int g = cb * 2 + (lane >> 5);
        atomicAdd(&stats[(n * GROUPS + g) * 2 + 0], s1);
        atomicAdd(&stats[(n * GROUPS + g) * 2 + 1], s2);
    }
}

__global__ __launch_bounds__(256)
void norm_bf16(const unsigned short* __restrict__ yb,
               const float* __restrict__ stats, float* __restrict__ out)
{
    const int total8 = 8 * COUT * SP_OUT / 8;
    const int grp8 = SP_OUT;
    const float inv_cnt = 1.0f / (8.0f * (float)SP_OUT);
    int idx = blockIdx.x * 256 + threadIdx.x;
    const int stride = gridDim.x * 256;
    for (int i = idx; i < total8; i += stride) {
        const int ng = i / grp8;
        const float m1 = stats[ng * 2 + 0] * inv_cnt;
        const float m2 = stats[ng * 2 + 1] * inv_cnt;
        const float rstd = rsqrtf(m2 - m1 * m1 + 1e-5f);
        const uint4 v = ((const uint4*)yb)[i];
        float4 o0, o1;
        o0.x = hswish((__uint_as_float((v.x & 0xffffu) << 16) - m1) * rstd);
        o0.y = hswish((__uint_as_float((v.x >> 16) << 16) - m1) * rstd);
        o0.z = hswish((__uint_as_float((v.y & 0xffffu) << 16) - m1) * rstd);
        o0.w = hswish((__uint_as_float((v.y >> 16) << 16) - m1) * rstd);
        o1.x = hswish((__uint_as_float((v.z & 0xffffu) << 16) - m1) * rstd);
        o1.y = hswish((__uint_as_float((v.z >> 16) << 16) - m1) * rstd);
        o1.z = hswish((__uint_as_float((v.w & 0xffffu) << 16) - m1) * rstd);
        o1.w = hswish((__uint_as_float((v.w >> 16) << 16) - m1) * rstd);
        ((float4*)out)[2 * i + 0] = o0;
        ((float4*)out)[2 * i + 1] = o1;
    }
}

__global__ __launch_bounds__(256)
void norm_ip(float* __restrict__ y, const float* __restrict__ stats)
{
    const int total4 = (8 * COUT * SP_OUT) / 4;
    const int grp4 = (8 * SP_OUT) / 4;
    const float inv_cnt = 1.0f / (8.0f * (float)SP_OUT);
    float4* p = (float4*)y;
    int idx = blockIdx.x * 256 + threadIdx.x;
    const int stride = gridDim.x * 256;
    for (int i = idx; i < total4; i += stride) {
        const int ng = i / grp4;
        const float m1 = stats[ng * 2 + 0] * inv_cnt;
        const float m2 = stats[ng * 2 + 1] * inv_cnt;
        const float rstd = rsqrtf(m2 - m1 * m1 + 1e-5f);
        float4 v = p[i];
        v.x = hswish((v.x - m1) * rstd);
        v.y = hswish((v.y - m1) * rstd);
        v.z = hswish((v.z - m1) * rstd);
        v.w = hswish((v.w - m1) * rstd);
        p[i] = v;
    }
}

extern "C" void kernel_launch(void* const* d_in, const int* in_sizes, int n_in,
                              void* d_out, int out_size, void* d_ws, size_t ws_size,
                              hipStream_t stream)
{
    const float* x    = (const float*)d_in[0];
    const float* w    = (const float*)d_in[1];
    const float* bias = (const float*)d_in[2];
    float* stats = (float*)d_ws;
    unsigned short* wpk = (unsigned short*)((char*)d_ws + WPK_OFF);

    repack_w<<<216, 256, 0, stream>>>(w, wpk, stats);

    dim3 grid(12 * 6, 1, 8);
    const size_t need = (size_t)Y_OFF + (size_t)8 * COUT * SP_OUT * 2;
    if (ws_size >= need) {
        char* ybf = (char*)d_ws + Y_OFF;
        conv_mfma<true><<<grid, 256, 0, stream>>>(x, wpk, bias, ybf, stats);
        norm_bf16<<<2048, 256, 0, stream>>>((const unsigned short*)ybf, stats, (float*)d_out);
    } else {
        conv_mfma<false><<<grid, 256, 0, stream>>>(x, wpk, bias, (char*)d_out, stats);
        norm_ip<<<2048, 256, 0, stream>>>((float*)d_out, stats);
    }
}